// Round 7
// baseline (404.575 us; speedup 1.0000x reference)
//
#include <hip/hip_runtime.h>
#include <hip/hip_fp16.h>

// Problem constants (fixed by the reference): B=4, D=8, H=512, W=640, 16 neighbors.
constexpr int BB = 4, DD = 8, HH = 512, WW = 640, NB = 16;
constexpr int NTOT = DD + NB;   // 24 values sorted per pixel
constexpr int HWST = HH * WW;   // channel stride (pixels per image)
constexpr size_t Q_BYTES = (size_t)BB * HWST * 8;   // fp16 quad texture: 10.5 MB

// Memory-op ordering fence (stops memory-op reordering only).
#define ISSUE_BARRIER() asm volatile("" ::: "memory")
// Machine-scheduler fence (no operands — operand-carrying asm crashes the
// toolchain on this setup; rounds 1 & 5 both died in the container with it).
#define SCHED_FENCE() __builtin_amdgcn_sched_barrier(0)

// Compile-time Batcher / Knuth merge-exchange sorting network for NTOT=24 (127 CEs).
struct Net { int a[160]; int b[160]; int n; };
constexpr Net make_net() {
    Net net{}; net.n = 0;
    const int N = NTOT;
    int t = 0; while ((1 << t) < N) ++t;
    for (int p = 1 << (t - 1); p > 0; p >>= 1) {
        int q = 1 << (t - 1), r = 0, d = p;
        for (;;) {
            for (int i = 0; i < N - d; ++i)
                if ((i & p) == r) { net.a[net.n] = i; net.b[net.n] = i + d; ++net.n; }
            if (q == p) break;
            d = q - p; q >>= 1; r = p;
        }
    }
    return net;
}

// ---------------------------------------------------------------------------
// Pre-pass: build fp16 quad texture Q[b][y][x] = {v00, v01, v10, v11} with
// border clamping baked in. 8B/entry, 2.6 MB per batch. Same XCD swizzle as
// the main kernel (b = bid & 3) so each quad image lands in the consuming L2s.
__global__ __launch_bounds__(128) void quad_prepass(
    const float* __restrict__ depth, uint2* __restrict__ Q)
{
    const int bid = blockIdx.x;                 // 0 .. 4*5*512-1
    const int b   = bid & 3;
    const int r   = bid >> 2;                   // 0 .. 2559
    const int wb  = r % 5;
    const int y   = r / 5;
    const int x   = wb * 128 + threadIdx.x;

    const float* __restrict__ img = depth + ((size_t)b * DD + DD / 2) * HWST;
    const int x1 = min(x + 1, WW - 1);
    const int y1 = min(y + 1, HH - 1);
    float v00 = img[y  * WW + x];
    float v01 = img[y  * WW + x1];
    float v10 = img[y1 * WW + x];
    float v11 = img[y1 * WW + x1];
    __half2 t = __floats2half2_rn(v00, v01);
    __half2 bo = __floats2half2_rn(v10, v11);
    uint2 q;
    q.x = *(const unsigned int*)&t;
    q.y = *(const unsigned int*)&bo;
    Q[(size_t)b * HWST + y * WW + x] = q;
}

// ---------------------------------------------------------------------------
// Main kernel: one thread per pixel. Bottleneck: ~21M independent random 8B
// L2 requests (divergent gathers) per dispatch. Two levers, now combined:
//   (1) deep per-thread MLP — fence-enforced 16-gather batches (R4/R6:
//       halved wave lifetime; flat beyond ~8-13 deep, so exhausted);
//   (2) residency — 128-thread blocks empirically hold ~21 waves/CU vs
//       ~12 for 256-thread blocks (R0-R3 vs R4/R6 occupancy 66% vs 37%).
// R4/R6 bought (1) by giving up (2); this version takes both. Chip-level
// in-flight requests = residency x per-wave depth -> expect ~2x concurrency.
//   * grid/depth loads + out stores: nontemporal streaming (zero reuse).
//   * Q gathers: AGENT-scope relaxed atomic -> global_load_dwordx2 sc0
//     (L1 bypass — 0% hit on 2.6MB random footprint — L2-allocating).
//   * fp16-packed bilinear weights (1 VGPR/neighbor; error << absmax).
//   * grid-wait -> gather-issue fused per-n (progressive vmcnt).
//   * no operand-carrying inline asm (toolchain killer, rounds 1/5).
__global__ __launch_bounds__(128, 6) void Propagation_kernel(
    const float* __restrict__ depth,   // [B, D, H, W]
    const float* __restrict__ grid,    // [B, NB*H, W, 2]
    const uint2* __restrict__ Q,       // [B, H, W] fp16 quads
    float* __restrict__ out)           // [B, D+NB, H, W] sorted along dim 1
{
    const int bid = blockIdx.x;        // 0 .. 10239
    const int b   = bid & 3;           // XCD = bid % 8 -> batch b on XCDs {b, b+4}
    const int r   = bid >> 2;          // 0 .. 2559
    const int hw  = r * 128 + threadIdx.x;   // linear pixel index, coalesced

    const uint2* __restrict__ Qb = Q + (size_t)b * HWST;
    const float* __restrict__ gbase = grid + ((size_t)b * NB * HWST + hw) * 2;

    // ---- Phase 0: issue ALL 16 grid loads (critical path to gather addrs).
    unsigned long long gbits[NB];
#pragma unroll
    for (int n = 0; n < NB; ++n)
        gbits[n] = __builtin_nontemporal_load(
            (const unsigned long long*)(gbase + (size_t)n * HWST * 2));
    ISSUE_BARRIER();

    // ---- Phase 1 (fused): per-n wait for gbits[n] (progressive vmcnt),
    // compute coords + packed fp16 weights, ISSUE gather n. Nothing consumes.
    unsigned int wpk[NB];              // (wx, wy) packed as __half2 — 1 VGPR/n
    unsigned long long qb[NB];
#pragma unroll
    for (int n = 0; n < NB; ++n) {
        float gx = __uint_as_float((unsigned int)gbits[n]);
        float gy = __uint_as_float((unsigned int)(gbits[n] >> 32));
        float x = ((gx + 1.0f) * (float)WW - 1.0f) * 0.5f;
        float y = ((gy + 1.0f) * (float)HH - 1.0f) * 0.5f;
        x = fminf(fmaxf(x, 0.0f), (float)(WW - 1));
        y = fminf(fmaxf(y, 0.0f), (float)(HH - 1));
        float x0f = floorf(x), y0f = floorf(y);
        __half2 wh = __floats2half2_rn(x - x0f, y - y0f);
        wpk[n] = __builtin_bit_cast(unsigned int, wh);
        const int off = (int)y0f * WW + (int)x0f;
        qb[n] = __hip_atomic_load((const unsigned long long*)(Qb + off),
                                  __ATOMIC_RELAXED, __HIP_MEMORY_SCOPE_AGENT);
    }
    // All 16 gathers in flight; forbid consumer hoisting above this point.
    SCHED_FENCE();

    // ---- Phase 2: depth streaming loads (consumed only at sort time) —
    // issued behind the gathers; latency hides under interpolation.
    float v[NTOT];
#pragma unroll
    for (int d = 0; d < DD; ++d)
        v[d] = __builtin_nontemporal_load(depth + ((size_t)b * DD + d) * HWST + hw);
    ISSUE_BARRIER();
    SCHED_FENCE();

    // ---- Phase 3: bilinear interpolation in fp32 (consumes qb[n] in issue
    // order; compiler emits progressive vmcnt waits).
#pragma unroll
    for (int n = 0; n < NB; ++n) {
        unsigned int lo = (unsigned int)qb[n];
        unsigned int hi = (unsigned int)(qb[n] >> 32);
        float2 t  = __half22float2(__builtin_bit_cast(__half2, lo));  // v00, v01
        float2 bo = __half22float2(__builtin_bit_cast(__half2, hi));  // v10, v11
        float2 wv = __half22float2(__builtin_bit_cast(__half2, wpk[n]));
        float ti = fmaf(wv.x, t.y - t.x, t.x);
        float bi = fmaf(wv.x, bo.y - bo.x, bo.x);
        v[DD + n] = fmaf(wv.y, bi - ti, ti);
    }

    // ---- Sort 24 values ascending (unrolled network; constant indices only).
    constexpr Net net = make_net();
#pragma unroll
    for (int k = 0; k < net.n; ++k) {
        const int ia = net.a[k], ib = net.b[k];
        float lo = fminf(v[ia], v[ib]);
        float hi = fmaxf(v[ia], v[ib]);
        v[ia] = lo; v[ib] = hi;
    }

    // ---- 24 coalesced nontemporal channel stores.
    float* __restrict__ obase = out + (size_t)b * NTOT * HWST + hw;
#pragma unroll
    for (int c = 0; c < NTOT; ++c)
        __builtin_nontemporal_store(v[c], obase + (size_t)c * HWST);
}

// ---------------------------------------------------------------------------
// Fallback (no workspace needed) in case ws_size < Q_BYTES.
__global__ __launch_bounds__(128) void Propagation_fallback(
    const float* __restrict__ depth, const float* __restrict__ grid,
    float* __restrict__ out)
{
    const int w = blockIdx.x * 128 + threadIdx.x;
    const int h = blockIdx.y;
    const int b = blockIdx.z;
    const int hw = h * WW + w;
    const float* __restrict__ img = depth + ((size_t)b * DD + DD / 2) * HWST;
    float v[NTOT];
#pragma unroll
    for (int d = 0; d < DD; ++d)
        v[d] = depth[((size_t)b * DD + d) * HWST + hw];
    const float* __restrict__ gbase = grid + (((size_t)b * NB * HH + h) * WW + w) * 2;
#pragma unroll
    for (int n = 0; n < NB; ++n) {
        float2 g = *(const float2*)(gbase + (size_t)n * HH * WW * 2);
        float x = ((g.x + 1.0f) * (float)WW - 1.0f) * 0.5f;
        float y = ((g.y + 1.0f) * (float)HH - 1.0f) * 0.5f;
        x = fminf(fmaxf(x, 0.0f), (float)(WW - 1));
        y = fminf(fmaxf(y, 0.0f), (float)(HH - 1));
        float x0f = floorf(x), y0f = floorf(y);
        float wx = x - x0f, wy = y - y0f;
        int x0 = (int)x0f, y0 = (int)y0f;
        float2 t, bo;
        __builtin_memcpy(&t,  img + y0 * WW + x0,      sizeof(float2));
        __builtin_memcpy(&bo, img + y0 * WW + x0 + WW, sizeof(float2));
        float ti = fmaf(wx, t.y - t.x, t.x);
        float bi = fmaf(wx, bo.y - bo.x, bo.x);
        v[DD + n] = fmaf(wy, bi - ti, ti);
    }
    constexpr Net net = make_net();
#pragma unroll
    for (int k = 0; k < net.n; ++k) {
        const int ia = net.a[k], ib = net.b[k];
        float lo = fminf(v[ia], v[ib]);
        float hi = fmaxf(v[ia], v[ib]);
        v[ia] = lo; v[ib] = hi;
    }
    float* __restrict__ obase = out + (size_t)b * NTOT * HWST + hw;
#pragma unroll
    for (int c = 0; c < NTOT; ++c)
        __builtin_nontemporal_store(v[c], obase + (size_t)c * HWST);
}

extern "C" void kernel_launch(void* const* d_in, const int* in_sizes, int n_in,
                              void* d_out, int out_size, void* d_ws, size_t ws_size,
                              hipStream_t stream) {
    const float* depth = (const float*)d_in[3];
    const float* grid  = (const float*)d_in[4];
    float* out = (float*)d_out;

    if (ws_size >= Q_BYTES) {
        uint2* Q = (uint2*)d_ws;
        quad_prepass<<<BB * (WW / 128) * HH, 128, 0, stream>>>(depth, Q);
        const int nblk = BB * (HWST / 128);   // 10240 blocks of 128 threads
        Propagation_kernel<<<nblk, 128, 0, stream>>>(depth, grid, Q, out);
    } else {
        dim3 grd(WW / 128, HH, BB);
        Propagation_fallback<<<grd, dim3(128), 0, stream>>>(depth, grid, out);
    }
}

// Round 8
// 377.635 us; speedup vs baseline: 1.0713x; 1.0713x over previous
//
#include <hip/hip_runtime.h>
#include <hip/hip_fp16.h>

// Problem constants (fixed by the reference): B=4, D=8, H=512, W=640, 16 neighbors.
constexpr int BB = 4, DD = 8, HH = 512, WW = 640, NB = 16;
constexpr int NTOT = DD + NB;   // 24 values sorted per pixel
constexpr int HWST = HH * WW;   // channel stride (pixels per image)
constexpr size_t Q_BYTES = (size_t)BB * HWST * 8;   // fp16 quad texture: 10.5 MB

// Memory-op ordering fence (stops memory-op reordering only).
#define ISSUE_BARRIER() asm volatile("" ::: "memory")
// Machine-scheduler fence (no operands — operand-carrying asm crashes the
// toolchain on this setup; rounds 1 & 5 both died in the container with it).
#define SCHED_FENCE() __builtin_amdgcn_sched_barrier(0)

// Compile-time Batcher / Knuth merge-exchange sorting network for NTOT=24 (127 CEs).
struct Net { int a[160]; int b[160]; int n; };
constexpr Net make_net() {
    Net net{}; net.n = 0;
    const int N = NTOT;
    int t = 0; while ((1 << t) < N) ++t;
    for (int p = 1 << (t - 1); p > 0; p >>= 1) {
        int q = 1 << (t - 1), r = 0, d = p;
        for (;;) {
            for (int i = 0; i < N - d; ++i)
                if ((i & p) == r) { net.a[net.n] = i; net.b[net.n] = i + d; ++net.n; }
            if (q == p) break;
            d = q - p; q >>= 1; r = p;
        }
    }
    return net;
}

// ---------------------------------------------------------------------------
// Pre-pass: build fp16 quad texture Q[b][y][x] = {v00, v01, v10, v11} with
// border clamping baked in. 8B/entry, 2.6 MB per batch. Same XCD swizzle as
// the main kernel (b = bid & 3) so each quad image lands in the consuming L2s.
__global__ __launch_bounds__(128) void quad_prepass(
    const float* __restrict__ depth, uint2* __restrict__ Q)
{
    const int bid = blockIdx.x;                 // 0 .. 4*5*512-1
    const int b   = bid & 3;
    const int r   = bid >> 2;                   // 0 .. 2559
    const int wb  = r % 5;
    const int y   = r / 5;
    const int x   = wb * 128 + threadIdx.x;

    const float* __restrict__ img = depth + ((size_t)b * DD + DD / 2) * HWST;
    const int x1 = min(x + 1, WW - 1);
    const int y1 = min(y + 1, HH - 1);
    float v00 = img[y  * WW + x];
    float v01 = img[y  * WW + x1];
    float v10 = img[y1 * WW + x];
    float v11 = img[y1 * WW + x1];
    __half2 t = __floats2half2_rn(v00, v01);
    __half2 bo = __floats2half2_rn(v10, v11);
    uint2 q;
    q.x = *(const unsigned int*)&t;
    q.y = *(const unsigned int*)&bo;
    Q[(size_t)b * HWST + y * WW + x] = q;
}

// ---------------------------------------------------------------------------
// Main kernel: one thread per pixel. Bottleneck: ~21M independent random 8B
// L2 requests (divergent gathers). Chip-level in-flight requests =
// residency x per-wave depth. Measured matrix so far:
//   shallow MLP x ~21 waves/CU (R0-R3, 128t): 151 us
//   16-deep MLP x ~12 waves/CU (R6, 256t):    141.6 us
//   spill-poisoned (R7, 128t + minwaves=6):   169 us (VGPR 40, +78MB traffic)
// This round: the unmeasured cell — 16-deep MLP x 128-thread residency,
// with PLAIN __launch_bounds__(128) so the allocator feels no pressure and
// cannot spill (R6 body needs ~56 VGPR; 64 VGPR x 8 waves/SIMD = full file).
//   * grid/depth loads + out stores: nontemporal streaming (zero reuse).
//   * Q gathers: AGENT-scope relaxed atomic -> global_load_dwordx2 sc0
//     (L1 bypass — 0% hit on 2.6MB random footprint — L2-allocating).
//   * fp16-packed bilinear weights (1 VGPR/neighbor; error << absmax).
//   * grid-wait -> gather-issue fused per-n (progressive vmcnt).
//   * no operand-carrying inline asm (toolchain killer, rounds 1/5).
__global__ __launch_bounds__(128) void Propagation_kernel(
    const float* __restrict__ depth,   // [B, D, H, W]
    const float* __restrict__ grid,    // [B, NB*H, W, 2]
    const uint2* __restrict__ Q,       // [B, H, W] fp16 quads
    float* __restrict__ out)           // [B, D+NB, H, W] sorted along dim 1
{
    const int bid = blockIdx.x;        // 0 .. 10239
    const int b   = bid & 3;           // XCD = bid % 8 -> batch b on XCDs {b, b+4}
    const int r   = bid >> 2;          // 0 .. 2559
    const int hw  = r * 128 + threadIdx.x;   // linear pixel index, coalesced

    const uint2* __restrict__ Qb = Q + (size_t)b * HWST;
    const float* __restrict__ gbase = grid + ((size_t)b * NB * HWST + hw) * 2;

    // ---- Phase 0: issue ALL 16 grid loads (critical path to gather addrs).
    unsigned long long gbits[NB];
#pragma unroll
    for (int n = 0; n < NB; ++n)
        gbits[n] = __builtin_nontemporal_load(
            (const unsigned long long*)(gbase + (size_t)n * HWST * 2));
    ISSUE_BARRIER();

    // ---- Phase 1 (fused): per-n wait for gbits[n] (progressive vmcnt),
    // compute coords + packed fp16 weights, ISSUE gather n. Nothing consumes.
    unsigned int wpk[NB];              // (wx, wy) packed as __half2 — 1 VGPR/n
    unsigned long long qb[NB];
#pragma unroll
    for (int n = 0; n < NB; ++n) {
        float gx = __uint_as_float((unsigned int)gbits[n]);
        float gy = __uint_as_float((unsigned int)(gbits[n] >> 32));
        float x = ((gx + 1.0f) * (float)WW - 1.0f) * 0.5f;
        float y = ((gy + 1.0f) * (float)HH - 1.0f) * 0.5f;
        x = fminf(fmaxf(x, 0.0f), (float)(WW - 1));
        y = fminf(fmaxf(y, 0.0f), (float)(HH - 1));
        float x0f = floorf(x), y0f = floorf(y);
        __half2 wh = __floats2half2_rn(x - x0f, y - y0f);
        wpk[n] = __builtin_bit_cast(unsigned int, wh);
        const int off = (int)y0f * WW + (int)x0f;
        qb[n] = __hip_atomic_load((const unsigned long long*)(Qb + off),
                                  __ATOMIC_RELAXED, __HIP_MEMORY_SCOPE_AGENT);
    }
    // All 16 gathers in flight; forbid consumer hoisting above this point.
    SCHED_FENCE();

    // ---- Phase 2: depth streaming loads (consumed only at sort time) —
    // issued behind the gathers; latency hides under interpolation.
    float v[NTOT];
#pragma unroll
    for (int d = 0; d < DD; ++d)
        v[d] = __builtin_nontemporal_load(depth + ((size_t)b * DD + d) * HWST + hw);
    ISSUE_BARRIER();
    SCHED_FENCE();

    // ---- Phase 3: bilinear interpolation in fp32 (consumes qb[n] in issue
    // order; compiler emits progressive vmcnt waits).
#pragma unroll
    for (int n = 0; n < NB; ++n) {
        unsigned int lo = (unsigned int)qb[n];
        unsigned int hi = (unsigned int)(qb[n] >> 32);
        float2 t  = __half22float2(__builtin_bit_cast(__half2, lo));  // v00, v01
        float2 bo = __half22float2(__builtin_bit_cast(__half2, hi));  // v10, v11
        float2 wv = __half22float2(__builtin_bit_cast(__half2, wpk[n]));
        float ti = fmaf(wv.x, t.y - t.x, t.x);
        float bi = fmaf(wv.x, bo.y - bo.x, bo.x);
        v[DD + n] = fmaf(wv.y, bi - ti, ti);
    }

    // ---- Sort 24 values ascending (unrolled network; constant indices only).
    constexpr Net net = make_net();
#pragma unroll
    for (int k = 0; k < net.n; ++k) {
        const int ia = net.a[k], ib = net.b[k];
        float lo = fminf(v[ia], v[ib]);
        float hi = fmaxf(v[ia], v[ib]);
        v[ia] = lo; v[ib] = hi;
    }

    // ---- 24 coalesced nontemporal channel stores.
    float* __restrict__ obase = out + (size_t)b * NTOT * HWST + hw;
#pragma unroll
    for (int c = 0; c < NTOT; ++c)
        __builtin_nontemporal_store(v[c], obase + (size_t)c * HWST);
}

// ---------------------------------------------------------------------------
// Fallback (no workspace needed) in case ws_size < Q_BYTES.
__global__ __launch_bounds__(128) void Propagation_fallback(
    const float* __restrict__ depth, const float* __restrict__ grid,
    float* __restrict__ out)
{
    const int w = blockIdx.x * 128 + threadIdx.x;
    const int h = blockIdx.y;
    const int b = blockIdx.z;
    const int hw = h * WW + w;
    const float* __restrict__ img = depth + ((size_t)b * DD + DD / 2) * HWST;
    float v[NTOT];
#pragma unroll
    for (int d = 0; d < DD; ++d)
        v[d] = depth[((size_t)b * DD + d) * HWST + hw];
    const float* __restrict__ gbase = grid + (((size_t)b * NB * HH + h) * WW + w) * 2;
#pragma unroll
    for (int n = 0; n < NB; ++n) {
        float2 g = *(const float2*)(gbase + (size_t)n * HH * WW * 2);
        float x = ((g.x + 1.0f) * (float)WW - 1.0f) * 0.5f;
        float y = ((g.y + 1.0f) * (float)HH - 1.0f) * 0.5f;
        x = fminf(fmaxf(x, 0.0f), (float)(WW - 1));
        y = fminf(fmaxf(y, 0.0f), (float)(HH - 1));
        float x0f = floorf(x), y0f = floorf(y);
        float wx = x - x0f, wy = y - y0f;
        int x0 = (int)x0f, y0 = (int)y0f;
        float2 t, bo;
        __builtin_memcpy(&t,  img + y0 * WW + x0,      sizeof(float2));
        __builtin_memcpy(&bo, img + y0 * WW + x0 + WW, sizeof(float2));
        float ti = fmaf(wx, t.y - t.x, t.x);
        float bi = fmaf(wx, bo.y - bo.x, bo.x);
        v[DD + n] = fmaf(wy, bi - ti, ti);
    }
    constexpr Net net = make_net();
#pragma unroll
    for (int k = 0; k < net.n; ++k) {
        const int ia = net.a[k], ib = net.b[k];
        float lo = fminf(v[ia], v[ib]);
        float hi = fmaxf(v[ia], v[ib]);
        v[ia] = lo; v[ib] = hi;
    }
    float* __restrict__ obase = out + (size_t)b * NTOT * HWST + hw;
#pragma unroll
    for (int c = 0; c < NTOT; ++c)
        __builtin_nontemporal_store(v[c], obase + (size_t)c * HWST);
}

extern "C" void kernel_launch(void* const* d_in, const int* in_sizes, int n_in,
                              void* d_out, int out_size, void* d_ws, size_t ws_size,
                              hipStream_t stream) {
    const float* depth = (const float*)d_in[3];
    const float* grid  = (const float*)d_in[4];
    float* out = (float*)d_out;

    if (ws_size >= Q_BYTES) {
        uint2* Q = (uint2*)d_ws;
        quad_prepass<<<BB * (WW / 128) * HH, 128, 0, stream>>>(depth, Q);
        const int nblk = BB * (HWST / 128);   // 10240 blocks of 128 threads
        Propagation_kernel<<<nblk, 128, 0, stream>>>(depth, grid, Q, out);
    } else {
        dim3 grd(WW / 128, HH, BB);
        Propagation_fallback<<<grd, dim3(128), 0, stream>>>(depth, grid, out);
    }
}